// Round 2
// baseline (415.129 us; speedup 1.0000x reference)
//
#include <hip/hip_runtime.h>
#include <stdint.h>

#define CC 256
#define HH 80
#define WW 80
#define PP 6400          // 80*80
#define GG 16
#define GNCNT (16*6400)  // per (n,group): 16 channels * 6400 pixels
#define SAPAD 272        // sA row stride in u16 (padded 256->272)

using frag_ab = __attribute__((ext_vector_type(8))) short;   // 8 bf16 (4 VGPRs)
using frag_cd = __attribute__((ext_vector_type(4))) float;   // 4 fp32
typedef unsigned short u16;

__device__ __forceinline__ float b2f(u16 u) {
    union { float f; uint32_t i; } v; v.i = ((uint32_t)u) << 16; return v.f;
}
__device__ __forceinline__ u16 f2b(float f) {
    uint32_t x = __float_as_uint(f);
    return (u16)((x + 0x7fffu + ((x >> 16) & 1u)) >> 16);  // RNE
}
__device__ __forceinline__ float sigf(float x) { return 1.f / (1.f + __expf(-x)); }

// plain fp32 -> bf16 (weights)
__global__ __launch_bounds__(256) void cvt_kernel(const float* __restrict__ src,
                                                  u16* __restrict__ dst, int n4) {
    int i = blockIdx.x * 256 + threadIdx.x;
    if (i < n4) {
        float4 v = ((const float4*)src)[i];
        ushort4 o;
        o.x = f2b(v.x); o.y = f2b(v.y); o.z = f2b(v.z); o.w = f2b(v.w);
        ((ushort4*)dst)[i] = o;
    }
}

// x [n][c][p] fp32 -> Xt [n][p][c] bf16.  64c x 64p tile per block.
__global__ __launch_bounds__(256) void cvtT_kernel(const float* __restrict__ x,
                                                   u16* __restrict__ Xt) {
    __shared__ u16 sT[64 * 72];   // [p][c], pad 64->72
    const int p0 = blockIdx.x * 64, c0 = blockIdx.y * 64, n = blockIdx.z;
    const int t = threadIdx.x;
    {   // phase 1: read x rows (coalesced along p), scatter bf16 into sT[p][c]
        const int cl = t >> 2, pq = t & 3;
        const float* row = x + ((size_t)(n * CC + c0 + cl)) * PP + p0 + pq * 16;
        #pragma unroll
        for (int u = 0; u < 4; u++) {
            float4 v = ((const float4*)(row + u * 4))[0];
            const int pp = pq * 16 + u * 4;
            sT[(pp + 0) * 72 + cl] = f2b(v.x);
            sT[(pp + 1) * 72 + cl] = f2b(v.y);
            sT[(pp + 2) * 72 + cl] = f2b(v.z);
            sT[(pp + 3) * 72 + cl] = f2b(v.w);
        }
    }
    __syncthreads();
    {   // phase 2: write Xt rows (coalesced along c)
        const int pl = t >> 2, cq = t & 3;
        u16* orow = Xt + ((size_t)(n * PP + p0 + pl)) * CC + c0 + cq * 16;
        *(frag_ab*)(orow)     = *(const frag_ab*)(sT + pl * 72 + cq * 16);
        *(frag_ab*)(orow + 8) = *(const frag_ab*)(sT + pl * 72 + cq * 16 + 8);
    }
}

// Out[m][o] = sum_c A[m][c] * W[o][c]; m = n*6400+p.
// CONCURRENCY FIX (round 2): round-1 proved the instruction stream is not the
// limiter (VGPR 96->80, occupancy 13->21%, time identical).  The kernel is
// latency-bound at 2 blocks/CU (reg bucket 256).  Diet: per wave 64m x 32o
// (acc[4][2]=32 regs, wf[2][8]=64 regs, peak live ~115 < 128) =>
// __launch_bounds__(256,4) = 4 blocks/CU.  o-range split across 2 blocks per
// m-tile (grid 1600).  W loads issued before the stage barrier.
// MODE 0/2: store bf16 + GN stats atomics (slot 0 / 1).  MODE 1: gate epilogue.
template<int MODE>
__global__ __launch_bounds__(256, 4) void gemm_kernel(
    const u16* __restrict__ A,       // [51200][256] bf16
    const u16* __restrict__ Wb,      // [256][256] bf16
    u16* __restrict__ Out,           // [51200][256] bf16
    float* __restrict__ stats,
    const u16* __restrict__ Hb,      // MODE1: h, same layout as A
    const float* __restrict__ Srow,  // MODE1: [8*80][256]
    const float* __restrict__ Scol,  // MODE1: [8*80][256]
    const float* __restrict__ bgate) // MODE1: [256]
{
    __shared__ __align__(16) u16 sA[64 * SAPAD];   // 34,816 B

    const int t    = threadIdx.x;
    const int lane = t & 63;
    const int wave = t >> 6;
    const int m    = lane & 15;
    const int q    = lane >> 4;
    const int mt   = blockIdx.x >> 1;    // m-tile index (0..799)
    const int oh   = blockIdx.x & 1;     // o-half (0/1)
    const int m0   = mt * 64;
    const int n    = mt / 100;           // 100 m-tiles of 64 rows per n
    const int o0w  = oh * 128 + wave * 32;   // wave's 32-o slice

    // ---- W fragments -> registers (16 x 16B), issued before the barrier ----
    frag_ab wf[2][8];
    {
        const u16* wl = Wb + (size_t)(o0w + m) * CC + q * 8;
        #pragma unroll
        for (int j = 0; j < 2; j++)
            #pragma unroll
            for (int kc = 0; kc < 8; kc++)
                wf[j][kc] = *(const frag_ab*)(wl + (size_t)(j * 16) * CC + kc * 32);
    }

    // ---- stage A chunk: 64 rows x 256 c, lane-contiguous loads ----
    {
        const int row = t >> 2, qt = t & 3;
        const u16* g = A + (size_t)(m0 + row) * CC + qt * 64;
        u16* d = sA + row * SAPAD + qt * 64;
        #pragma unroll
        for (int i = 0; i < 8; i++)
            *(frag_ab*)(d + i * 8) = *(const frag_ab*)(g + i * 8);
    }
    // pin W fragments so they cannot be sunk past the barrier
    #pragma unroll
    for (int j = 0; j < 2; j++)
        #pragma unroll
        for (int kc = 0; kc < 8; kc++)
            asm volatile("" : "+v"(wf[j][kc]));
    __syncthreads();

    frag_cd acc[4][2];   // [msub][j]
    #pragma unroll
    for (int ms = 0; ms < 4; ms++)
        #pragma unroll
        for (int j = 0; j < 2; j++)
            #pragma unroll
            for (int k = 0; k < 4; k++) acc[ms][j][k] = 0.f;

    #pragma unroll
    for (int ms = 0; ms < 4; ms++) {
        #pragma unroll
        for (int kc = 0; kc < 8; kc++) {
            frag_ab af = *(const frag_ab*)(sA + (ms * 16 + m) * SAPAD + kc * 32 + q * 8);
            acc[ms][0] = __builtin_amdgcn_mfma_f32_16x16x32_bf16(af, wf[0][kc], acc[ms][0], 0, 0, 0);
            acc[ms][1] = __builtin_amdgcn_mfma_f32_16x16x32_bf16(af, wf[1][kc], acc[ms][1], 0, 0, 0);
        }
    }
    __syncthreads();   // all waves done reading sA; reuse as epilogue scratch

    if (MODE == 0 || MODE == 2) {
        float* st = stats + (MODE == 2 ? 256 : 0);
        #pragma unroll
        for (int j = 0; j < 2; j++) {
            float s = 0.f, sq = 0.f;
            #pragma unroll
            for (int ms = 0; ms < 4; ms++)
                #pragma unroll
                for (int r = 0; r < 4; r++) {
                    float v = acc[ms][j][r];
                    s += v; sq += v * v;
                }
            #pragma unroll
            for (int off = 32; off > 0; off >>= 1) {
                s  += __shfl_down(s, off);
                sq += __shfl_down(sq, off);
            }
            if (lane == 0) {
                const int g = (o0w >> 4) + j;
                atomicAdd(&st[n * GG + g], s);
                atomicAdd(&st[128 + n * GG + g], sq);
            }
        }
        // repack per 16-row subtile through private slab -> 16B stores
        u16* myT = sA + wave * 640;   // 16 x 40 u16 slab
        #pragma unroll
        for (int ms = 0; ms < 4; ms++) {
            #pragma unroll
            for (int j = 0; j < 2; j++)
                #pragma unroll
                for (int r = 0; r < 4; r++)
                    myT[(q * 4 + r) * 40 + j * 16 + m] = f2b(acc[ms][j][r]);
            {
                const int rr = lane >> 2, ch = lane & 3;
                frag_ab v = *(const frag_ab*)(myT + rr * 40 + ch * 8);
                *(frag_ab*)(Out + (size_t)(m0 + ms * 16 + rr) * CC + o0w + ch * 8) = v;
            }
        }
    } else {
        float* myG = (float*)sA + wave * 576;   // 16 x 36 fp32 slab
        float bg[2];
        #pragma unroll
        for (int j = 0; j < 2; j++) bg[j] = bgate[o0w + j * 16 + m];
        #pragma unroll
        for (int ms = 0; ms < 4; ms++) {
            #pragma unroll
            for (int j = 0; j < 2; j++)
                #pragma unroll
                for (int r = 0; r < 4; r++)
                    myG[(q * 4 + r) * 36 + j * 16 + m] = sigf(acc[ms][j][r] + bg[j]);
            {
                const int rr  = lane >> 2, ch = lane & 3;
                const int row = m0 + ms * 16 + rr;
                const int pl  = row - n * PP;
                const int pr  = pl / WW;
                const int pc  = pl - pr * WW;
                const int o   = o0w + ch * 8;
                float4 ga = *(const float4*)(myG + rr * 36 + ch * 8);
                float4 gb = *(const float4*)(myG + rr * 36 + ch * 8 + 4);
                frag_ab hv = *(const frag_ab*)(Hb + (size_t)row * CC + o);
                float4 sra = *(const float4*)(Srow + (size_t)(n * HH + pr) * CC + o);
                float4 srb = *(const float4*)(Srow + (size_t)(n * HH + pr) * CC + o + 4);
                float4 sca = *(const float4*)(Scol + (size_t)(n * HH + pc) * CC + o);
                float4 scb = *(const float4*)(Scol + (size_t)(n * HH + pc) * CC + o + 4);
                frag_ab ov;
                ov[0] = (short)f2b(0.25f * (sra.x + sca.x + 2.f * b2f((u16)hv[0])) * ga.x);
                ov[1] = (short)f2b(0.25f * (sra.y + sca.y + 2.f * b2f((u16)hv[1])) * ga.y);
                ov[2] = (short)f2b(0.25f * (sra.z + sca.z + 2.f * b2f((u16)hv[2])) * ga.z);
                ov[3] = (short)f2b(0.25f * (sra.w + sca.w + 2.f * b2f((u16)hv[3])) * ga.w);
                ov[4] = (short)f2b(0.25f * (srb.x + scb.x + 2.f * b2f((u16)hv[4])) * gb.x);
                ov[5] = (short)f2b(0.25f * (srb.y + scb.y + 2.f * b2f((u16)hv[5])) * gb.y);
                ov[6] = (short)f2b(0.25f * (srb.z + scb.z + 2.f * b2f((u16)hv[6])) * gb.z);
                ov[7] = (short)f2b(0.25f * (srb.w + scb.w + 2.f * b2f((u16)hv[7])) * gb.w);
                *(frag_ab*)(Out + (size_t)row * CC + o) = ov;
            }
        }
    }
}

// GN1 + SiLU + Srow.  Block per (i-row, n): 80 j x 256 c.
__global__ __launch_bounds__(256) void gn1_kernel(
    const u16* __restrict__ c1, u16* __restrict__ hb,
    float* __restrict__ Srow,
    const float* __restrict__ stats,
    const float* __restrict__ g1, const float* __restrict__ b1)
{
    __shared__ float sred[8 * 256];
    const int i = blockIdx.x, n = blockIdx.y;
    const int t = threadIdx.x;
    const int jg = t >> 5, cc = t & 31;
    const int c8 = cc * 8;
    const int g  = cc >> 1;   // 8c chunk within one 16c group
    const float su   = stats[n * GG + g];
    const float sq   = stats[128 + n * GG + g];
    const float mean = su * (1.f / GNCNT);
    const float var  = sq * (1.f / GNCNT) - mean * mean;
    const float inv  = rsqrtf(var + 1e-5f);
    float a[8], b[8];
    #pragma unroll
    for (int k = 0; k < 8; k++) {
        a[k] = inv * g1[c8 + k];
        b[k] = b1[c8 + k] - mean * a[k];
    }
    float srow8[8];
    #pragma unroll
    for (int k = 0; k < 8; k++) srow8[k] = 0.f;

    const size_t base = (size_t)(n * PP + i * WW) * CC;
    for (int s = 0; s < 10; s++) {
        const int j = jg + s * 8;
        const u16* src = c1 + base + (size_t)j * CC + c8;
        u16*       dst = hb + base + (size_t)j * CC + c8;
        frag_ab v = *(const frag_ab*)src;
        frag_ab o;
        #pragma unroll
        for (int k = 0; k < 8; k++) {
            float xn = b2f((u16)v[k]) * a[k] + b[k];
            float hs = xn * sigf(xn);
            o[k] = (short)f2b(hs);
            srow8[k] += hs;
        }
        *(frag_ab*)dst = o;
    }
    #pragma unroll
    for (int k = 0; k < 8; k++) sred[jg * 256 + c8 + k] = srow8[k];
    __syncthreads();
    {
        const int c = t;
        float s = 0.f;
        #pragma unroll
        for (int k = 0; k < 8; k++) s += sred[k * 256 + c];
        Srow[(size_t)(n * HH + i) * CC + c] = s;
    }
}

// Scol[n][j][c] = sum_i hs[n][i*80+j][c].  Block (jg, iq, n); atomics (Scol pre-zeroed).
__global__ __launch_bounds__(256) void scol_kernel(
    const u16* __restrict__ hb, float* __restrict__ Scol)
{
    const int jg = blockIdx.x, iq = blockIdx.y, n = blockIdx.z;
    const int t = threadIdx.x;
    const int js = t >> 5, cc = t & 31;
    const int j = jg * 8 + js, c8 = cc * 8;
    float acc8[8];
    #pragma unroll
    for (int k = 0; k < 8; k++) acc8[k] = 0.f;
    for (int s = 0; s < 20; s++) {
        const int i = iq * 20 + s;
        frag_ab v = *(const frag_ab*)(hb + (size_t)(n * PP + i * WW + j) * CC + c8);
        #pragma unroll
        for (int k = 0; k < 8; k++) acc8[k] += b2f((u16)v[k]);
    }
    float* dst = Scol + (size_t)(n * HH + j) * CC + c8;
    #pragma unroll
    for (int k = 0; k < 8; k++) atomicAdd(&dst[k], acc8[k]);
}

// depthwise 3x3 zero-pad in [p][c] layout.  Block (i, chalf, n).
__global__ __launch_bounds__(256) void dw_kernel(
    const u16* __restrict__ gin, u16* __restrict__ dout,
    const float* __restrict__ wdw)
{
    __shared__ float sw[1152];   // 128 c * 9
    const int i = blockIdx.x, chalf = blockIdx.y, n = blockIdx.z;
    const int t = threadIdx.x;
    for (int u = t; u < 1152; u += 256) sw[u] = wdw[chalf * 1152 + u];
    __syncthreads();

    const int jg = t >> 5, cc = t & 31;
    const int gc = chalf * 128 + cc * 4;   // global c of 4-chunk
    float wl[4][9];
    #pragma unroll
    for (int cl = 0; cl < 4; cl++)
        #pragma unroll
        for (int k = 0; k < 9; k++) wl[cl][k] = sw[(cc * 4 + cl) * 9 + k];

    const size_t nbase = (size_t)n * PP * CC;
    for (int s = 0; s < 10; s++) {
        const int j = jg + s * 8;
        float acc4[4] = {0.f, 0.f, 0.f, 0.f};
        #pragma unroll
        for (int di = -1; di <= 1; di++) {
            const int ii = i + di;
            if (ii < 0 || ii >= HH) continue;
            #pragma unroll
            for (int dj = -1; dj <= 1; dj++) {
                const int jj = j + dj;
                if (jj < 0 || jj >= WW) continue;
                ushort4 v = *(const ushort4*)(gin + nbase + (size_t)(ii * WW + jj) * CC + gc);
                const int k = (di + 1) * 3 + (dj + 1);
                acc4[0] += wl[0][k] * b2f(v.x);
                acc4[1] += wl[1][k] * b2f(v.y);
                acc4[2] += wl[2][k] * b2f(v.z);
                acc4[3] += wl[3][k] * b2f(v.w);
            }
        }
        ushort4 o;
        o.x = f2b(acc4[0]); o.y = f2b(acc4[1]); o.z = f2b(acc4[2]); o.w = f2b(acc4[3]);
        *(ushort4*)(dout + nbase + (size_t)(i * WW + j) * CC + gc) = o;
    }
}

// GN2 + SiLU + transpose-out: Y [n][p][c] bf16 -> out [n][c][p] fp32.  64p x 64c tile.
__global__ __launch_bounds__(256) void gn2T_kernel(
    const u16* __restrict__ Y, float* __restrict__ out,
    const float* __restrict__ stats,
    const float* __restrict__ g2, const float* __restrict__ b2v)
{
    __shared__ u16 sT[64 * 72];
    const int p0 = blockIdx.x * 64, c0 = blockIdx.y * 64, n = blockIdx.z;
    const int t = threadIdx.x;
    {   // phase 1: read Y rows (coalesced along c)
        const int pl = t >> 2, cq = t & 3;
        const u16* row = Y + (size_t)(n * PP + p0 + pl) * CC + c0 + cq * 16;
        *(frag_ab*)(sT + pl * 72 + cq * 16)     = *(const frag_ab*)(row);
        *(frag_ab*)(sT + pl * 72 + cq * 16 + 8) = *(const frag_ab*)(row + 8);
    }
    __syncthreads();
    {   // phase 2: per-c affine + silu, write out rows (coalesced along p)
        const int cl = t >> 2, pq = t & 3;
        const int c = c0 + cl, g = c >> 4;
        const float su   = stats[256 + n * GG + g];
        const float sq   = stats[384 + n * GG + g];
        const float mean = su * (1.f / GNCNT);
        const float var  = sq * (1.f / GNCNT) - mean * mean;
        const float inv  = rsqrtf(var + 1e-5f);
        const float a    = inv * g2[c];
        const float b    = b2v[c] - mean * a;
        float* orow = out + (size_t)(n * CC + c) * PP + p0 + pq * 16;
        #pragma unroll
        for (int u4 = 0; u4 < 4; u4++) {
            float4 o;
            float* op = (float*)&o;
            #pragma unroll
            for (int e = 0; e < 4; e++) {
                const int pp = pq * 16 + u4 * 4 + e;
                float xn = b2f(sT[pp * 72 + cl]) * a + b;
                op[e] = xn * sigf(xn);
            }
            ((float4*)(orow + u4 * 4))[0] = o;
        }
    }
}

extern "C" void kernel_launch(void* const* d_in, const int* in_sizes, int n_in,
                              void* d_out, int out_size, void* d_ws, size_t ws_size,
                              hipStream_t stream)
{
    const float* x      = (const float*)d_in[0];
    const float* w_pre  = (const float*)d_in[1];
    const float* g1     = (const float*)d_in[2];
    const float* b1     = (const float*)d_in[3];
    const float* w_gate = (const float*)d_in[4];
    const float* b_gate = (const float*)d_in[5];
    const float* w_dw   = (const float*)d_in[6];
    const float* w_pw   = (const float*)d_in[7];
    const float* g2     = (const float*)d_in[8];
    const float* b2     = (const float*)d_in[9];
    float* out = (float*)d_out;

    char* ws = (char*)d_ws;
    u16*   wb0   = (u16*)(ws);                      // 131,072 B
    u16*   wb1   = (u16*)(ws + 131072);             // 131,072 B
    u16*   wb2   = (u16*)(ws + 262144);             // 131,072 B
    u16*   Xt    = (u16*)(ws + 393216);             // 26,214,400 B
    u16*   bufA  = (u16*)(ws + 26607616);           // 26,214,400 B
    u16*   bufB  = (u16*)(ws + 52822016);           // 26,214,400 B
    float* Srow  = (float*)(ws + 79036416);         // 655,360 B
    float* Scol  = (float*)(ws + 79691776);         // 655,360 B
    float* stats = (float*)(ws + 80347136);         // 2,048 B

    hipMemsetAsync(stats, 0, 2048, stream);
    hipMemsetAsync(Scol, 0, 655360, stream);

    cvt_kernel<<<64, 256, 0, stream>>>(w_pre,  wb0, 16384);
    cvt_kernel<<<64, 256, 0, stream>>>(w_gate, wb1, 16384);
    cvt_kernel<<<64, 256, 0, stream>>>(w_pw,   wb2, 16384);
    cvtT_kernel<<<dim3(100, 4, 8), 256, 0, stream>>>(x, Xt);

    // grid: 1600 blocks = 800 m-tiles x 2 o-halves; 4 blocks/CU
    // conv1 + GN1 stats
    gemm_kernel<0><<<1600, 256, 0, stream>>>(Xt, wb0, bufA, stats,
                                             nullptr, nullptr, nullptr, nullptr);
    // GN1 + SiLU + Srow
    gn1_kernel<<<dim3(80, 8), 256, 0, stream>>>(bufA, bufB, Srow, stats, g1, b1);
    // Scol
    scol_kernel<<<dim3(10, 4, 8), 256, 0, stream>>>(bufB, Scol);
    // gate conv + fused-scan gating
    gemm_kernel<1><<<1600, 256, 0, stream>>>(bufB, wb1, bufA, stats,
                                             bufB, Srow, Scol, b_gate);
    // depthwise 3x3
    dw_kernel<<<dim3(80, 2, 8), 256, 0, stream>>>(bufA, bufB, w_dw);
    // conv3 + GN2 stats
    gemm_kernel<2><<<1600, 256, 0, stream>>>(bufB, wb2, bufA, stats,
                                             nullptr, nullptr, nullptr, nullptr);
    // GN2 + SiLU -> fp32 out (transposed)
    gn2T_kernel<<<dim3(100, 4, 8), 256, 0, stream>>>(bufA, out, stats, g2, b2);
}

// Round 3
// 412.576 us; speedup vs baseline: 1.0062x; 1.0062x over previous
//
#include <hip/hip_runtime.h>
#include <stdint.h>

#define CC 256
#define HH 80
#define WW 80
#define PP 6400          // 80*80
#define GG 16
#define GNCNT (16*6400)  // per (n,group): 16 channels * 6400 pixels

using frag_ab = __attribute__((ext_vector_type(8))) short;   // 8 bf16 (4 VGPRs)
using frag_cd = __attribute__((ext_vector_type(4))) float;   // 4 fp32
typedef unsigned short u16;

__device__ __forceinline__ float b2f(u16 u) {
    union { float f; uint32_t i; } v; v.i = ((uint32_t)u) << 16; return v.f;
}
__device__ __forceinline__ u16 f2b(float f) {
    uint32_t x = __float_as_uint(f);
    return (u16)((x + 0x7fffu + ((x >> 16) & 1u)) >> 16);  // RNE
}
__device__ __forceinline__ float sigf(float x) { return 1.f / (1.f + __expf(-x)); }

// plain fp32 -> bf16 (weights)
__global__ __launch_bounds__(256) void cvt_kernel(const float* __restrict__ src,
                                                  u16* __restrict__ dst, int n4) {
    int i = blockIdx.x * 256 + threadIdx.x;
    if (i < n4) {
        float4 v = ((const float4*)src)[i];
        ushort4 o;
        o.x = f2b(v.x); o.y = f2b(v.y); o.z = f2b(v.z); o.w = f2b(v.w);
        ((ushort4*)dst)[i] = o;
    }
}

// x [n][c][p] fp32 -> Xt [n][p][c] bf16.  64c x 64p tile per block.
__global__ __launch_bounds__(256) void cvtT_kernel(const float* __restrict__ x,
                                                   u16* __restrict__ Xt) {
    __shared__ u16 sT[64 * 72];   // [p][c], pad 64->72
    const int p0 = blockIdx.x * 64, c0 = blockIdx.y * 64, n = blockIdx.z;
    const int t = threadIdx.x;
    {   // phase 1: read x rows (coalesced along p), scatter bf16 into sT[p][c]
        const int cl = t >> 2, pq = t & 3;
        const float* row = x + ((size_t)(n * CC + c0 + cl)) * PP + p0 + pq * 16;
        #pragma unroll
        for (int u = 0; u < 4; u++) {
            float4 v = ((const float4*)(row + u * 4))[0];
            const int pp = pq * 16 + u * 4;
            sT[(pp + 0) * 72 + cl] = f2b(v.x);
            sT[(pp + 1) * 72 + cl] = f2b(v.y);
            sT[(pp + 2) * 72 + cl] = f2b(v.z);
            sT[(pp + 3) * 72 + cl] = f2b(v.w);
        }
    }
    __syncthreads();
    {   // phase 2: write Xt rows (coalesced along c)
        const int pl = t >> 2, cq = t & 3;
        u16* orow = Xt + ((size_t)(n * PP + p0 + pl)) * CC + c0 + cq * 16;
        *(frag_ab*)(orow)     = *(const frag_ab*)(sT + pl * 72 + cq * 16);
        *(frag_ab*)(orow + 8) = *(const frag_ab*)(sT + pl * 72 + cq * 16 + 8);
    }
}

// ---------------------------------------------------------------------------
// GEMM: Out[m][o] = sum_c A[m][c] * W[o][c]; m = n*6400+p.
// Round-3 structure: per block 64m x 256o (A read ONCE), grid 512, each block
// owns tiles {bid, bid+512}.  A staged via global_load_lds (16B DMA, linear
// LDS dest + inverse-XOR-swizzled global source; read side applies the same
// XOR).  Tile-1 DMA is issued up front and kept in flight across tile-0's
// compute+epilogue via counted s_waitcnt vmcnt(8) + raw s_barrier (no
// __syncthreads vmcnt(0) drain).  W fragments wf[4][8] (128 VGPR, pinned)
// loaded before the DMAs.  MODE1 reads Hb from LDS (same tile!) -25.6 MB.
// ---------------------------------------------------------------------------

__device__ __forceinline__ void stage_tile(const u16* __restrict__ A, int m0,
                                           u16* buf, int wave, int lane) {
    #pragma unroll
    for (int it = 0; it < 8; ++it) {
        const int base = wave * 8192 + it * 1024;       // wave-uniform LDS byte base
        const int doff = base + lane * 16;              // this lane's dest byte
        const int row  = doff >> 9;                     // 512 B per A row
        const int cb   = doff & 511;
        const char* src = (const char*)A + (size_t)(m0 + row) * 512
                          + (cb ^ ((row & 7) << 4));    // inverse swizzle on source
        __builtin_amdgcn_global_load_lds(
            (const __attribute__((address_space(1))) uint32_t*)src,
            (__attribute__((address_space(3))) uint32_t*)((char*)buf + base),
            16, 0, 0);
    }
}

template<int MODE>
__device__ __forceinline__ void compute_tile(
    u16* buf, int mt,
    const frag_ab (&wf)[4][8],
    u16* __restrict__ Out, float* __restrict__ stats,
    const float* __restrict__ Srow, const float* __restrict__ Scol,
    const float (&bg)[4],
    int lane, int wave, int m, int q)
{
    const char* bufb = (const char*)buf;
    const int m0  = mt * 64;
    const int n   = mt / 100;
    const int o0w = wave * 64;
    const int sx  = (m & 7) << 4;   // read-side swizzle (row&7, ms*16 neutral)

    frag_cd acc[4][4];
    #pragma unroll
    for (int ms = 0; ms < 4; ms++)
        #pragma unroll
        for (int j = 0; j < 4; j++)
            #pragma unroll
            for (int k = 0; k < 4; k++) acc[ms][j][k] = 0.f;

    #pragma unroll
    for (int ms = 0; ms < 4; ms++) {
        #pragma unroll
        for (int kc = 0; kc < 8; kc++) {
            frag_ab af = *(const frag_ab*)(bufb + (ms * 16 + m) * 512
                                           + ((kc * 64 + q * 16) ^ sx));
            #pragma unroll
            for (int j = 0; j < 4; j++)
                acc[ms][j] = __builtin_amdgcn_mfma_f32_16x16x32_bf16(
                    af, wf[j][kc], acc[ms][j], 0, 0, 0);
        }
    }
    // all waves done reading A rows; buf reusable as epilogue scratch.
    // raw barrier + lgkm drain only -- keep the other tile's DMA in flight.
    asm volatile("s_waitcnt lgkmcnt(0)\n\ts_barrier" ::: "memory");

    if (MODE == 0 || MODE == 2) {
        float* st = stats + (MODE == 2 ? 256 : 0);
        #pragma unroll
        for (int j = 0; j < 4; j++) {
            float s = 0.f, sq = 0.f;
            #pragma unroll
            for (int ms = 0; ms < 4; ms++)
                #pragma unroll
                for (int r = 0; r < 4; r++) {
                    float v = acc[ms][j][r];
                    s += v; sq += v * v;
                }
            #pragma unroll
            for (int off = 32; off > 0; off >>= 1) {
                s  += __shfl_down(s, off);
                sq += __shfl_down(sq, off);
            }
            if (lane == 0) {
                const int g = (o0w >> 4) + j;
                atomicAdd(&st[n * GG + g], s);
                atomicAdd(&st[128 + n * GG + g], sq);
            }
        }
        // repack per 16-row subtile through private slab -> 16B stores
        u16* myT = buf + wave * 1152;   // 16x72 u16 slab (rows 0..17 of buf, dead)
        #pragma unroll
        for (int ms = 0; ms < 4; ms++) {
            #pragma unroll
            for (int j = 0; j < 4; j++)
                #pragma unroll
                for (int r = 0; r < 4; r++)
                    myT[(q * 4 + r) * 72 + j * 16 + m] = f2b(acc[ms][j][r]);
            #pragma unroll
            for (int u = 0; u < 2; u++) {
                const int rr = u * 8 + (lane >> 3);
                frag_ab v = *(const frag_ab*)(myT + rr * 72 + (lane & 7) * 8);
                *(frag_ab*)(Out + (size_t)(m0 + ms * 16 + rr) * CC + o0w + (lane & 7) * 8) = v;
            }
        }
    } else {
        // gate epilogue.  Hb tile == this A tile: prefetch hv from LDS (swizzled),
        // barrier, then slab transpose may overwrite buf rows.
        ushort4 hv[4][4];
        {
            const int rr0 = lane >> 4;
            const int c8b = o0w * 2 + (lane & 15) * 8;   // byte col of 8B chunk
            #pragma unroll
            for (int ms = 0; ms < 4; ms++)
                #pragma unroll
                for (int u = 0; u < 4; u++) {
                    const int row = ms * 16 + u * 4 + rr0;
                    hv[ms][u] = *(const ushort4*)(bufb + row * 512
                                                  + (c8b ^ ((row & 7) << 4)));
                }
        }
        asm volatile("s_waitcnt lgkmcnt(0)\n\ts_barrier" ::: "memory");

        float* myG = (float*)buf + wave * 1152;   // 16x72 fp32 slab
        #pragma unroll
        for (int ms = 0; ms < 4; ms++) {
            #pragma unroll
            for (int j = 0; j < 4; j++)
                #pragma unroll
                for (int r = 0; r < 4; r++)
                    myG[(q * 4 + r) * 72 + j * 16 + m] = sigf(acc[ms][j][r] + bg[j]);
            #pragma unroll
            for (int u = 0; u < 4; u++) {
                const int rr  = u * 4 + (lane >> 4);
                const int col = (lane & 15) * 4;
                float4 g4 = *(const float4*)(myG + rr * 72 + col);
                const int row = m0 + ms * 16 + rr;
                const int pl  = row - n * PP;
                const int pr  = pl / WW;
                const int pc  = pl - pr * WW;
                const int o   = o0w + col;
                ushort4 hq = hv[ms][u];
                float4  sr = *(const float4*)(Srow + (size_t)(n * HH + pr) * CC + o);
                float4  sc = *(const float4*)(Scol + (size_t)(n * HH + pc) * CC + o);
                ushort4 ov;
                ov.x = f2b(0.25f * (sr.x + sc.x + 2.f * b2f(hq.x)) * g4.x);
                ov.y = f2b(0.25f * (sr.y + sc.y + 2.f * b2f(hq.y)) * g4.y);
                ov.z = f2b(0.25f * (sr.z + sc.z + 2.f * b2f(hq.z)) * g4.z);
                ov.w = f2b(0.25f * (sr.w + sc.w + 2.f * b2f(hq.w)) * g4.w);
                *(ushort4*)(Out + (size_t)row * CC + o) = ov;
            }
        }
    }
}

template<int MODE>
__global__ __launch_bounds__(256, 2) void gemm_kernel(
    const u16* __restrict__ A,       // [51200][256] bf16
    const u16* __restrict__ Wb,      // [256][256] bf16
    u16* __restrict__ Out,           // [51200][256] bf16
    float* __restrict__ stats,
    const u16* __restrict__ Hb,      // MODE1: == A (read from LDS now)
    const float* __restrict__ Srow,  // MODE1: [8*80][256]
    const float* __restrict__ Scol,  // MODE1: [8*80][256]
    const float* __restrict__ bgate) // MODE1: [256]
{
    __shared__ __align__(16) u16 sA0[64 * 256];   // 32 KiB (linear, swizzled content)
    __shared__ __align__(16) u16 sA1[64 * 256];   // 32 KiB

    const int t    = threadIdx.x;
    const int lane = t & 63;
    const int wave = t >> 6;
    const int m    = lane & 15;
    const int q    = lane >> 4;
    const int mt0  = blockIdx.x;          // grid 512; tiles bid and bid+512
    const int mt1  = blockIdx.x + 512;
    const int o0w  = wave * 64;

    // ---- W fragments -> 128 VGPRs, pinned; issued BEFORE the DMAs so the
    //      compiler's wf-waits count only the W loads (in-order vmcnt). ----
    frag_ab wf[4][8];
    {
        const u16* wl = Wb + (size_t)(o0w + m) * CC + q * 8;
        #pragma unroll
        for (int j = 0; j < 4; j++)
            #pragma unroll
            for (int kc = 0; kc < 8; kc++)
                wf[j][kc] = *(const frag_ab*)(wl + (size_t)(j * 16) * CC + kc * 32);
    }
    #pragma unroll
    for (int j = 0; j < 4; j++)
        #pragma unroll
        for (int kc = 0; kc < 8; kc++)
            asm volatile("" : "+v"(wf[j][kc]));

    float bg[4] = {0.f, 0.f, 0.f, 0.f};
    if (MODE == 1) {
        #pragma unroll
        for (int j = 0; j < 4; j++) bg[j] = bgate[o0w + j * 16 + m];
    }

    asm volatile("" ::: "memory");   // keep W loads ordered before the DMAs
    stage_tile(A, mt0 * 64, sA0, wave, lane);
    if (mt1 < 800) {
        stage_tile(A, mt1 * 64, sA1, wave, lane);
        // 8 newest outstanding VMEM = tile-1 DMA; tile-0 (and W) drained.
        asm volatile("s_waitcnt vmcnt(8)\n\ts_barrier" ::: "memory");
    } else {
        asm volatile("s_waitcnt vmcnt(0)\n\ts_barrier" ::: "memory");
    }

    compute_tile<MODE>(sA0, mt0, wf, Out, stats, Srow, Scol, bg, lane, wave, m, q);

    if (mt1 < 800) {
        asm volatile("s_waitcnt vmcnt(0)\n\ts_barrier" ::: "memory");
        compute_tile<MODE>(sA1, mt1, wf, Out, stats, Srow, Scol, bg, lane, wave, m, q);
    }
}

// GN1 + SiLU + Srow.  Block per (i-row, n): 80 j x 256 c.
__global__ __launch_bounds__(256) void gn1_kernel(
    const u16* __restrict__ c1, u16* __restrict__ hb,
    float* __restrict__ Srow,
    const float* __restrict__ stats,
    const float* __restrict__ g1, const float* __restrict__ b1)
{
    __shared__ float sred[8 * 256];
    const int i = blockIdx.x, n = blockIdx.y;
    const int t = threadIdx.x;
    const int jg = t >> 5, cc = t & 31;
    const int c8 = cc * 8;
    const int g  = cc >> 1;   // 8c chunk within one 16c group
    const float su   = stats[n * GG + g];
    const float sq   = stats[128 + n * GG + g];
    const float mean = su * (1.f / GNCNT);
    const float var  = sq * (1.f / GNCNT) - mean * mean;
    const float inv  = rsqrtf(var + 1e-5f);
    float a[8], b[8];
    #pragma unroll
    for (int k = 0; k < 8; k++) {
        a[k] = inv * g1[c8 + k];
        b[k] = b1[c8 + k] - mean * a[k];
    }
    float srow8[8];
    #pragma unroll
    for (int k = 0; k < 8; k++) srow8[k] = 0.f;

    const size_t base = (size_t)(n * PP + i * WW) * CC;
    for (int s = 0; s < 10; s++) {
        const int j = jg + s * 8;
        const u16* src = c1 + base + (size_t)j * CC + c8;
        u16*       dst = hb + base + (size_t)j * CC + c8;
        frag_ab v = *(const frag_ab*)src;
        frag_ab o;
        #pragma unroll
        for (int k = 0; k < 8; k++) {
            float xn = b2f((u16)v[k]) * a[k] + b[k];
            float hs = xn * sigf(xn);
            o[k] = (short)f2b(hs);
            srow8[k] += hs;
        }
        *(frag_ab*)dst = o;
    }
    #pragma unroll
    for (int k = 0; k < 8; k++) sred[jg * 256 + c8 + k] = srow8[k];
    __syncthreads();
    {
        const int c = t;
        float s = 0.f;
        #pragma unroll
        for (int k = 0; k < 8; k++) s += sred[k * 256 + c];
        Srow[(size_t)(n * HH + i) * CC + c] = s;
    }
}

// Scol[n][j][c] = sum_i hs[n][i*80+j][c].  Block (jg, iq, n); atomics (Scol pre-zeroed).
__global__ __launch_bounds__(256) void scol_kernel(
    const u16* __restrict__ hb, float* __restrict__ Scol)
{
    const int jg = blockIdx.x, iq = blockIdx.y, n = blockIdx.z;
    const int t = threadIdx.x;
    const int js = t >> 5, cc = t & 31;
    const int j = jg * 8 + js, c8 = cc * 8;
    float acc8[8];
    #pragma unroll
    for (int k = 0; k < 8; k++) acc8[k] = 0.f;
    for (int s = 0; s < 20; s++) {
        const int i = iq * 20 + s;
        frag_ab v = *(const frag_ab*)(hb + (size_t)(n * PP + i * WW + j) * CC + c8);
        #pragma unroll
        for (int k = 0; k < 8; k++) acc8[k] += b2f((u16)v[k]);
    }
    float* dst = Scol + (size_t)(n * HH + j) * CC + c8;
    #pragma unroll
    for (int k = 0; k < 8; k++) atomicAdd(&dst[k], acc8[k]);
}

// depthwise 3x3 zero-pad in [p][c] layout.  Block (i, chalf, n).
__global__ __launch_bounds__(256) void dw_kernel(
    const u16* __restrict__ gin, u16* __restrict__ dout,
    const float* __restrict__ wdw)
{
    __shared__ float sw[1152];   // 128 c * 9
    const int i = blockIdx.x, chalf = blockIdx.y, n = blockIdx.z;
    const int t = threadIdx.x;
    for (int u = t; u < 1152; u += 256) sw[u] = wdw[chalf * 1152 + u];
    __syncthreads();

    const int jg = t >> 5, cc = t & 31;
    const int gc = chalf * 128 + cc * 4;   // global c of 4-chunk
    float wl[4][9];
    #pragma unroll
    for (int cl = 0; cl < 4; cl++)
        #pragma unroll
        for (int k = 0; k < 9; k++) wl[cl][k] = sw[(cc * 4 + cl) * 9 + k];

    const size_t nbase = (size_t)n * PP * CC;
    for (int s = 0; s < 10; s++) {
        const int j = jg + s * 8;
        float acc4[4] = {0.f, 0.f, 0.f, 0.f};
        #pragma unroll
        for (int di = -1; di <= 1; di++) {
            const int ii = i + di;
            if (ii < 0 || ii >= HH) continue;
            #pragma unroll
            for (int dj = -1; dj <= 1; dj++) {
                const int jj = j + dj;
                if (jj < 0 || jj >= WW) continue;
                ushort4 v = *(const ushort4*)(gin + nbase + (size_t)(ii * WW + jj) * CC + gc);
                const int k = (di + 1) * 3 + (dj + 1);
                acc4[0] += wl[0][k] * b2f(v.x);
                acc4[1] += wl[1][k] * b2f(v.y);
                acc4[2] += wl[2][k] * b2f(v.z);
                acc4[3] += wl[3][k] * b2f(v.w);
            }
        }
        ushort4 o;
        o.x = f2b(acc4[0]); o.y = f2b(acc4[1]); o.z = f2b(acc4[2]); o.w = f2b(acc4[3]);
        *(ushort4*)(dout + nbase + (size_t)(i * WW + j) * CC + gc) = o;
    }
}

// GN2 + SiLU + transpose-out: Y [n][p][c] bf16 -> out [n][c][p] fp32.  64p x 64c tile.
__global__ __launch_bounds__(256) void gn2T_kernel(
    const u16* __restrict__ Y, float* __restrict__ out,
    const float* __restrict__ stats,
    const float* __restrict__ g2, const float* __restrict__ b2v)
{
    __shared__ u16 sT[64 * 72];
    const int p0 = blockIdx.x * 64, c0 = blockIdx.y * 64, n = blockIdx.z;
    const int t = threadIdx.x;
    {   // phase 1: read Y rows (coalesced along c)
        const int pl = t >> 2, cq = t & 3;
        const u16* row = Y + (size_t)(n * PP + p0 + pl) * CC + c0 + cq * 16;
        *(frag_ab*)(sT + pl * 72 + cq * 16)     = *(const frag_ab*)(row);
        *(frag_ab*)(sT + pl * 72 + cq * 16 + 8) = *(const frag_ab*)(row + 8);
    }
    __syncthreads();
    {   // phase 2: per-c affine + silu, write out rows (coalesced along p)
        const int cl = t >> 2, pq = t & 3;
        const int c = c0 + cl, g = c >> 4;
        const float su   = stats[256 + n * GG + g];
        const float sq   = stats[384 + n * GG + g];
        const float mean = su * (1.f / GNCNT);
        const float var  = sq * (1.f / GNCNT) - mean * mean;
        const float inv  = rsqrtf(var + 1e-5f);
        const float a    = inv * g2[c];
        const float b    = b2v[c] - mean * a;
        float* orow = out + (size_t)(n * CC + c) * PP + p0 + pq * 16;
        #pragma unroll
        for (int u4 = 0; u4 < 4; u4++) {
            float4 o;
            float* op = (float*)&o;
            #pragma unroll
            for (int e = 0; e < 4; e++) {
                const int pp = pq * 16 + u4 * 4 + e;
                float xn = b2f(sT[pp * 72 + cl]) * a + b;
                op[e] = xn * sigf(xn);
            }
            ((float4*)(orow + u4 * 4))[0] = o;
        }
    }
}

extern "C" void kernel_launch(void* const* d_in, const int* in_sizes, int n_in,
                              void* d_out, int out_size, void* d_ws, size_t ws_size,
                              hipStream_t stream)
{
    const float* x      = (const float*)d_in[0];
    const float* w_pre  = (const float*)d_in[1];
    const float* g1     = (const float*)d_in[2];
    const float* b1     = (const float*)d_in[3];
    const float* w_gate = (const float*)d_in[4];
    const float* b_gate = (const float*)d_in[5];
    const float* w_dw   = (const float*)d_in[6];
    const float* w_pw   = (const float*)d_in[7];
    const float* g2     = (const float*)d_in[8];
    const float* b2     = (const float*)d_in[9];
    float* out = (float*)d_out;

    char* ws = (char*)d_ws;
    u16*   wb0   = (u16*)(ws);                      // 131,072 B
    u16*   wb1   = (u16*)(ws + 131072);             // 131,072 B
    u16*   wb2   = (u16*)(ws + 262144);             // 131,072 B
    u16*   Xt    = (u16*)(ws + 393216);             // 26,214,400 B
    u16*   bufA  = (u16*)(ws + 26607616);           // 26,214,400 B
    u16*   bufB  = (u16*)(ws + 52822016);           // 26,214,400 B
    float* Srow  = (float*)(ws + 79036416);         // 655,360 B
    float* Scol  = (float*)(ws + 79691776);         // 655,360 B
    float* stats = (float*)(ws + 80347136);         // 2,048 B

    hipMemsetAsync(stats, 0, 2048, stream);
    hipMemsetAsync(Scol, 0, 655360, stream);

    cvt_kernel<<<64, 256, 0, stream>>>(w_pre,  wb0, 16384);
    cvt_kernel<<<64, 256, 0, stream>>>(w_gate, wb1, 16384);
    cvt_kernel<<<64, 256, 0, stream>>>(w_pw,   wb2, 16384);
    cvtT_kernel<<<dim3(100, 4, 8), 256, 0, stream>>>(x, Xt);

    // grid 512: block owns tiles {bid, bid+512}; tile-1 DMA pipelined under tile-0
    // conv1 + GN1 stats
    gemm_kernel<0><<<512, 256, 0, stream>>>(Xt, wb0, bufA, stats,
                                            nullptr, nullptr, nullptr, nullptr);
    // GN1 + SiLU + Srow
    gn1_kernel<<<dim3(80, 8), 256, 0, stream>>>(bufA, bufB, Srow, stats, g1, b1);
    // Scol
    scol_kernel<<<dim3(10, 4, 8), 256, 0, stream>>>(bufB, Scol);
    // gate conv + fused-scan gating (Hb == A tile, read from LDS)
    gemm_kernel<1><<<512, 256, 0, stream>>>(bufB, wb1, bufA, stats,
                                            bufB, Srow, Scol, b_gate);
    // depthwise 3x3
    dw_kernel<<<dim3(80, 2, 8), 256, 0, stream>>>(bufA, bufB, w_dw);
    // conv3 + GN2 stats
    gemm_kernel<2><<<512, 256, 0, stream>>>(bufB, wb2, bufA, stats,
                                            nullptr, nullptr, nullptr, nullptr);
    // GN2 + SiLU -> fp32 out (transposed)
    gn2T_kernel<<<dim3(100, 4, 8), 256, 0, stream>>>(bufA, out, stats, g2, b2);
}

// Round 4
// 319.542 us; speedup vs baseline: 1.2991x; 1.2911x over previous
//
#include <hip/hip_runtime.h>
#include <stdint.h>

#define CC 256
#define HH 80
#define WW 80
#define PP 6400          // 80*80
#define GG 16
#define GNCNT (16*6400)  // per (n,group): 16 channels * 6400 pixels
#define SAPAD 272        // sA row stride in u16 (padded 256->272)

using frag_ab = __attribute__((ext_vector_type(8))) short;   // 8 bf16 (4 VGPRs)
using frag_cd = __attribute__((ext_vector_type(4))) float;   // 4 fp32
typedef unsigned short u16;

__device__ __forceinline__ float b2f(u16 u) {
    union { float f; uint32_t i; } v; v.i = ((uint32_t)u) << 16; return v.f;
}
__device__ __forceinline__ u16 f2b(float f) {
    uint32_t x = __float_as_uint(f);
    return (u16)((x + 0x7fffu + ((x >> 16) & 1u)) >> 16);  // RNE
}
__device__ __forceinline__ float sigf(float x) { return 1.f / (1.f + __expf(-x)); }

// plain fp32 -> bf16 (weights)
__global__ __launch_bounds__(256) void cvt_kernel(const float* __restrict__ src,
                                                  u16* __restrict__ dst, int n4) {
    int i = blockIdx.x * 256 + threadIdx.x;
    if (i < n4) {
        float4 v = ((const float4*)src)[i];
        ushort4 o;
        o.x = f2b(v.x); o.y = f2b(v.y); o.z = f2b(v.z); o.w = f2b(v.w);
        ((ushort4*)dst)[i] = o;
    }
}

// x [n][c][p] fp32 -> Xt [n][p][c] bf16.  64c x 64p tile per block.
__global__ __launch_bounds__(256) void cvtT_kernel(const float* __restrict__ x,
                                                   u16* __restrict__ Xt) {
    __shared__ u16 sT[64 * 72];   // [p][c], pad 64->72
    const int p0 = blockIdx.x * 64, c0 = blockIdx.y * 64, n = blockIdx.z;
    const int t = threadIdx.x;
    {   // phase 1: read x rows (coalesced along p), scatter bf16 into sT[p][c]
        const int cl = t >> 2, pq = t & 3;
        const float* row = x + ((size_t)(n * CC + c0 + cl)) * PP + p0 + pq * 16;
        #pragma unroll
        for (int u = 0; u < 4; u++) {
            float4 v = ((const float4*)(row + u * 4))[0];
            const int pp = pq * 16 + u * 4;
            sT[(pp + 0) * 72 + cl] = f2b(v.x);
            sT[(pp + 1) * 72 + cl] = f2b(v.y);
            sT[(pp + 2) * 72 + cl] = f2b(v.z);
            sT[(pp + 3) * 72 + cl] = f2b(v.w);
        }
    }
    __syncthreads();
    {   // phase 2: write Xt rows (coalesced along c)
        const int pl = t >> 2, cq = t & 3;
        u16* orow = Xt + ((size_t)(n * PP + p0 + pl)) * CC + c0 + cq * 16;
        *(frag_ab*)(orow)     = *(const frag_ab*)(sT + pl * 72 + cq * 16);
        *(frag_ab*)(orow + 8) = *(const frag_ab*)(sT + pl * 72 + cq * 16 + 8);
    }
}

// Out[m][o] = sum_c A[m][c] * W[o][c]; m = n*6400+p.
// Block: 64 m-rows x ALL 256 o (A read once).  Per wave: 64-o slice in two
// 32-o halves (wf[2][8] = 64 VGPRs each, pinned).  ROUND-4 CHANGE: the
// GN-stats atomicAdd storm (16,384 device-scope fp32 atomics into 16 cache
// lines => ~60-80us serialized tail, the structure-independent floor seen in
// rounds 0-3) is replaced by contention-free per-block partial writes to
// pstats[mt*32 + kind*16 + group_local]; a tiny reduce kernel sums the 100
// blocks per n afterwards.
// MODE 0/2: store bf16 + partial-stats writes.  MODE 1: gate epilogue.
template<int MODE>
__global__ __launch_bounds__(256, 2) void gemm_kernel(
    const u16* __restrict__ A,       // [51200][256] bf16
    const u16* __restrict__ Wb,      // [256][256] bf16
    u16* __restrict__ Out,           // [51200][256] bf16
    float* __restrict__ pstats,      // MODE0/2: [800][32] per-block partials
    const u16* __restrict__ Hb,      // MODE1: h, same layout as A
    const float* __restrict__ Srow,  // MODE1: [8*80][256]
    const float* __restrict__ Scol,  // MODE1: [8*80][256]
    const float* __restrict__ bgate) // MODE1: [256]
{
    __shared__ __align__(16) u16 sA[64 * SAPAD];   // 34,816 B

    const int t    = threadIdx.x;
    const int lane = t & 63;
    const int wave = t >> 6;
    const int m    = lane & 15;
    const int q    = lane >> 4;
    const int mt   = blockIdx.x;
    const int m0   = mt * 64;
    const int n    = mt / 100;   // 100 blocks of 64 rows per n
    const int o0w  = wave * 64;  // wave's o-slice

    // ---- stage A chunk: 64 rows x 256 c, lane-contiguous loads ----
    {
        const int row = t >> 2, qt = t & 3;
        const u16* g = A + (size_t)(m0 + row) * CC + qt * 64;
        u16* d = sA + row * SAPAD + qt * 64;
        #pragma unroll
        for (int i = 0; i < 8; i++)
            *(frag_ab*)(d + i * 8) = *(const frag_ab*)(g + i * 8);
    }
    __syncthreads();

    frag_cd acc[4][4];   // [msub][j]
    #pragma unroll
    for (int ms = 0; ms < 4; ms++)
        #pragma unroll
        for (int j = 0; j < 4; j++)
            #pragma unroll
            for (int k = 0; k < 4; k++) acc[ms][j][k] = 0.f;

    const u16* wl = Wb + (size_t)(o0w + m) * CC + q * 8;

    #pragma unroll
    for (int jh = 0; jh < 2; jh++) {
        // ---- W fragments for this 32-o half -> 64 VGPRs, one parallel batch ----
        frag_ab wf[2][8];
        #pragma unroll
        for (int jj = 0; jj < 2; jj++)
            #pragma unroll
            for (int kc = 0; kc < 8; kc++)
                wf[jj][kc] = *(const frag_ab*)(wl + (size_t)((jh * 2 + jj) * 16) * CC + kc * 32);
        // pin: forbid rematerialization/sinking of the W loads
        #pragma unroll
        for (int jj = 0; jj < 2; jj++)
            #pragma unroll
            for (int kc = 0; kc < 8; kc++)
                asm volatile("" : "+v"(wf[jj][kc]));

        #pragma unroll
        for (int ms = 0; ms < 4; ms++) {
            #pragma unroll
            for (int kc = 0; kc < 8; kc++) {
                frag_ab af = *(const frag_ab*)(sA + (ms * 16 + m) * SAPAD + kc * 32 + q * 8);
                #pragma unroll
                for (int jj = 0; jj < 2; jj++)
                    acc[ms][jh * 2 + jj] = __builtin_amdgcn_mfma_f32_16x16x32_bf16(
                        af, wf[jj][kc], acc[ms][jh * 2 + jj], 0, 0, 0);
            }
        }
    }
    __syncthreads();   // all waves done reading sA; reuse as epilogue scratch

    if (MODE == 0 || MODE == 2) {
        #pragma unroll
        for (int j = 0; j < 4; j++) {
            float s = 0.f, sq = 0.f;
            #pragma unroll
            for (int ms = 0; ms < 4; ms++)
                #pragma unroll
                for (int r = 0; r < 4; r++) {
                    float v = acc[ms][j][r];
                    s += v; sq += v * v;
                }
            #pragma unroll
            for (int off = 32; off > 0; off >>= 1) {
                s  += __shfl_down(s, off);
                sq += __shfl_down(sq, off);
            }
            if (lane == 0) {
                // contention-free per-block partials (group = wave*4 + j)
                float* p = pstats + (size_t)mt * 32;
                p[wave * 4 + j]      = s;
                p[16 + wave * 4 + j] = sq;
            }
        }
        // repack per 16-row subtile through private slab -> 16B stores
        u16* myT = sA + wave * 1152;   // 16x72 u16
        #pragma unroll
        for (int ms = 0; ms < 4; ms++) {
            #pragma unroll
            for (int j = 0; j < 4; j++)
                #pragma unroll
                for (int r = 0; r < 4; r++)
                    myT[(q * 4 + r) * 72 + j * 16 + m] = f2b(acc[ms][j][r]);
            #pragma unroll
            for (int u = 0; u < 2; u++) {
                const int rr = u * 8 + (lane >> 3);
                frag_ab v = *(const frag_ab*)(myT + rr * 72 + (lane & 7) * 8);
                *(frag_ab*)(Out + (size_t)(m0 + ms * 16 + rr) * CC + o0w + (lane & 7) * 8) = v;
            }
        }
    } else {
        float* myG = (float*)sA + wave * 1152;   // 16x72 fp32
        float bg[4];
        #pragma unroll
        for (int j = 0; j < 4; j++) bg[j] = bgate[o0w + j * 16 + m];
        #pragma unroll
        for (int ms = 0; ms < 4; ms++) {
            #pragma unroll
            for (int j = 0; j < 4; j++)
                #pragma unroll
                for (int r = 0; r < 4; r++)
                    myG[(q * 4 + r) * 72 + j * 16 + m] = sigf(acc[ms][j][r] + bg[j]);
            #pragma unroll
            for (int u = 0; u < 4; u++) {
                const int rr  = u * 4 + (lane >> 4);
                const int col = (lane & 15) * 4;
                float4 g4 = *(const float4*)(myG + rr * 72 + col);
                const int row = m0 + ms * 16 + rr;
                const int pl  = row - n * PP;
                const int pr  = pl / WW;
                const int pc  = pl - pr * WW;
                const int o   = o0w + col;
                ushort4 hv = *(const ushort4*)(Hb + (size_t)row * CC + o);
                float4  sr = *(const float4*)(Srow + (size_t)(n * HH + pr) * CC + o);
                float4  sc = *(const float4*)(Scol + (size_t)(n * HH + pc) * CC + o);
                ushort4 ov;
                ov.x = f2b(0.25f * (sr.x + sc.x + 2.f * b2f(hv.x)) * g4.x);
                ov.y = f2b(0.25f * (sr.y + sc.y + 2.f * b2f(hv.y)) * g4.y);
                ov.z = f2b(0.25f * (sr.z + sc.z + 2.f * b2f(hv.z)) * g4.z);
                ov.w = f2b(0.25f * (sr.w + sc.w + 2.f * b2f(hv.w)) * g4.w);
                *(ushort4*)(Out + (size_t)row * CC + o) = ov;
            }
        }
    }
}

// Reduce per-block partials -> stats.  1 block, 256 threads.
// t = kind*128 + n*16 + g; sums pscr[(n*100+i)*32 + kind*16 + g] over i.
__global__ __launch_bounds__(256) void reduce_stats_kernel(
    const float* __restrict__ pscr, float* __restrict__ stats_out)
{
    const int t = threadIdx.x;
    const int g = t & 15, n = (t >> 4) & 7, kind = t >> 7;
    float s = 0.f;
    #pragma unroll 4
    for (int i = 0; i < 100; i++)
        s += pscr[(size_t)(n * 100 + i) * 32 + kind * 16 + g];
    stats_out[t] = s;   // sum -> [n*16+g], sq -> [128 + n*16+g]
}

// GN1 + SiLU + Srow.  Block per (i-row, n): 80 j x 256 c.
__global__ __launch_bounds__(256) void gn1_kernel(
    const u16* __restrict__ c1, u16* __restrict__ hb,
    float* __restrict__ Srow,
    const float* __restrict__ stats,
    const float* __restrict__ g1, const float* __restrict__ b1)
{
    __shared__ float sred[8 * 256];
    const int i = blockIdx.x, n = blockIdx.y;
    const int t = threadIdx.x;
    const int jg = t >> 5, cc = t & 31;
    const int c8 = cc * 8;
    const int g  = cc >> 1;   // 8c chunk within one 16c group
    const float su   = stats[n * GG + g];
    const float sq   = stats[128 + n * GG + g];
    const float mean = su * (1.f / GNCNT);
    const float var  = sq * (1.f / GNCNT) - mean * mean;
    const float inv  = rsqrtf(var + 1e-5f);
    float a[8], b[8];
    #pragma unroll
    for (int k = 0; k < 8; k++) {
        a[k] = inv * g1[c8 + k];
        b[k] = b1[c8 + k] - mean * a[k];
    }
    float srow8[8];
    #pragma unroll
    for (int k = 0; k < 8; k++) srow8[k] = 0.f;

    const size_t base = (size_t)(n * PP + i * WW) * CC;
    for (int s = 0; s < 10; s++) {
        const int j = jg + s * 8;
        const u16* src = c1 + base + (size_t)j * CC + c8;
        u16*       dst = hb + base + (size_t)j * CC + c8;
        frag_ab v = *(const frag_ab*)src;
        frag_ab o;
        #pragma unroll
        for (int k = 0; k < 8; k++) {
            float xn = b2f((u16)v[k]) * a[k] + b[k];
            float hs = xn * sigf(xn);
            o[k] = (short)f2b(hs);
            srow8[k] += hs;
        }
        *(frag_ab*)dst = o;
    }
    #pragma unroll
    for (int k = 0; k < 8; k++) sred[jg * 256 + c8 + k] = srow8[k];
    __syncthreads();
    {
        const int c = t;
        float s = 0.f;
        #pragma unroll
        for (int k = 0; k < 8; k++) s += sred[k * 256 + c];
        Srow[(size_t)(n * HH + i) * CC + c] = s;
    }
}

// Scol[n][j][c] = sum_i hs[n][i*80+j][c].  Block (jg, iq, n); atomics (Scol pre-zeroed).
__global__ __launch_bounds__(256) void scol_kernel(
    const u16* __restrict__ hb, float* __restrict__ Scol)
{
    const int jg = blockIdx.x, iq = blockIdx.y, n = blockIdx.z;
    const int t = threadIdx.x;
    const int js = t >> 5, cc = t & 31;
    const int j = jg * 8 + js, c8 = cc * 8;
    float acc8[8];
    #pragma unroll
    for (int k = 0; k < 8; k++) acc8[k] = 0.f;
    for (int s = 0; s < 20; s++) {
        const int i = iq * 20 + s;
        frag_ab v = *(const frag_ab*)(hb + (size_t)(n * PP + i * WW + j) * CC + c8);
        #pragma unroll
        for (int k = 0; k < 8; k++) acc8[k] += b2f((u16)v[k]);
    }
    float* dst = Scol + (size_t)(n * HH + j) * CC + c8;
    #pragma unroll
    for (int k = 0; k < 8; k++) atomicAdd(&dst[k], acc8[k]);
}

// depthwise 3x3 zero-pad in [p][c] layout.  Block (i, chalf, n).
__global__ __launch_bounds__(256) void dw_kernel(
    const u16* __restrict__ gin, u16* __restrict__ dout,
    const float* __restrict__ wdw)
{
    __shared__ float sw[1152];   // 128 c * 9
    const int i = blockIdx.x, chalf = blockIdx.y, n = blockIdx.z;
    const int t = threadIdx.x;
    for (int u = t; u < 1152; u += 256) sw[u] = wdw[chalf * 1152 + u];
    __syncthreads();

    const int jg = t >> 5, cc = t & 31;
    const int gc = chalf * 128 + cc * 4;   // global c of 4-chunk
    float wl[4][9];
    #pragma unroll
    for (int cl = 0; cl < 4; cl++)
        #pragma unroll
        for (int k = 0; k < 9; k++) wl[cl][k] = sw[(cc * 4 + cl) * 9 + k];

    const size_t nbase = (size_t)n * PP * CC;
    for (int s = 0; s < 10; s++) {
        const int j = jg + s * 8;
        float acc4[4] = {0.f, 0.f, 0.f, 0.f};
        #pragma unroll
        for (int di = -1; di <= 1; di++) {
            const int ii = i + di;
            if (ii < 0 || ii >= HH) continue;
            #pragma unroll
            for (int dj = -1; dj <= 1; dj++) {
                const int jj = j + dj;
                if (jj < 0 || jj >= WW) continue;
                ushort4 v = *(const ushort4*)(gin + nbase + (size_t)(ii * WW + jj) * CC + gc);
                const int k = (di + 1) * 3 + (dj + 1);
                acc4[0] += wl[0][k] * b2f(v.x);
                acc4[1] += wl[1][k] * b2f(v.y);
                acc4[2] += wl[2][k] * b2f(v.z);
                acc4[3] += wl[3][k] * b2f(v.w);
            }
        }
        ushort4 o;
        o.x = f2b(acc4[0]); o.y = f2b(acc4[1]); o.z = f2b(acc4[2]); o.w = f2b(acc4[3]);
        *(ushort4*)(dout + nbase + (size_t)(i * WW + j) * CC + gc) = o;
    }
}

// GN2 + SiLU + transpose-out: Y [n][p][c] bf16 -> out [n][c][p] fp32.  64p x 64c tile.
__global__ __launch_bounds__(256) void gn2T_kernel(
    const u16* __restrict__ Y, float* __restrict__ out,
    const float* __restrict__ stats,
    const float* __restrict__ g2, const float* __restrict__ b2v)
{
    __shared__ u16 sT[64 * 72];
    const int p0 = blockIdx.x * 64, c0 = blockIdx.y * 64, n = blockIdx.z;
    const int t = threadIdx.x;
    {   // phase 1: read Y rows (coalesced along c)
        const int pl = t >> 2, cq = t & 3;
        const u16* row = Y + (size_t)(n * PP + p0 + pl) * CC + c0 + cq * 16;
        *(frag_ab*)(sT + pl * 72 + cq * 16)     = *(const frag_ab*)(row);
        *(frag_ab*)(sT + pl * 72 + cq * 16 + 8) = *(const frag_ab*)(row + 8);
    }
    __syncthreads();
    {   // phase 2: per-c affine + silu, write out rows (coalesced along p)
        const int cl = t >> 2, pq = t & 3;
        const int c = c0 + cl, g = c >> 4;
        const float su   = stats[256 + n * GG + g];
        const float sq   = stats[384 + n * GG + g];
        const float mean = su * (1.f / GNCNT);
        const float var  = sq * (1.f / GNCNT) - mean * mean;
        const float inv  = rsqrtf(var + 1e-5f);
        const float a    = inv * g2[c];
        const float b    = b2v[c] - mean * a;
        float* orow = out + (size_t)(n * CC + c) * PP + p0 + pq * 16;
        #pragma unroll
        for (int u4 = 0; u4 < 4; u4++) {
            float4 o;
            float* op = (float*)&o;
            #pragma unroll
            for (int e = 0; e < 4; e++) {
                const int pp = pq * 16 + u4 * 4 + e;
                float xn = b2f(sT[pp * 72 + cl]) * a + b;
                op[e] = xn * sigf(xn);
            }
            ((float4*)(orow + u4 * 4))[0] = o;
        }
    }
}

extern "C" void kernel_launch(void* const* d_in, const int* in_sizes, int n_in,
                              void* d_out, int out_size, void* d_ws, size_t ws_size,
                              hipStream_t stream)
{
    const float* x      = (const float*)d_in[0];
    const float* w_pre  = (const float*)d_in[1];
    const float* g1     = (const float*)d_in[2];
    const float* b1     = (const float*)d_in[3];
    const float* w_gate = (const float*)d_in[4];
    const float* b_gate = (const float*)d_in[5];
    const float* w_dw   = (const float*)d_in[6];
    const float* w_pw   = (const float*)d_in[7];
    const float* g2     = (const float*)d_in[8];
    const float* b2     = (const float*)d_in[9];
    float* out = (float*)d_out;

    char* ws = (char*)d_ws;
    u16*   wb0   = (u16*)(ws);                      // 131,072 B
    u16*   wb1   = (u16*)(ws + 131072);             // 131,072 B
    u16*   wb2   = (u16*)(ws + 262144);             // 131,072 B
    u16*   Xt    = (u16*)(ws + 393216);             // 26,214,400 B
    u16*   bufA  = (u16*)(ws + 26607616);           // 26,214,400 B
    u16*   bufB  = (u16*)(ws + 52822016);           // 26,214,400 B
    float* Srow  = (float*)(ws + 79036416);         // 655,360 B
    float* Scol  = (float*)(ws + 79691776);         // 655,360 B
    float* stats = (float*)(ws + 80347136);         // 2,048 B

    // per-block stats partials, carved from buffers that are DEAD at the time:
    //  - pscr0 (gemm0 partials): head of bufB (bufB written first by gn1, AFTER reduce0)
    //  - pscr1 (gemm2 partials): head of Xt   (Xt dead after gemm0)
    float* pscr0 = (float*)bufB;   // 102,400 B
    float* pscr1 = (float*)Xt;     // 102,400 B

    hipMemsetAsync(Scol, 0, 655360, stream);

    cvt_kernel<<<64, 256, 0, stream>>>(w_pre,  wb0, 16384);
    cvt_kernel<<<64, 256, 0, stream>>>(w_gate, wb1, 16384);
    cvt_kernel<<<64, 256, 0, stream>>>(w_pw,   wb2, 16384);
    cvtT_kernel<<<dim3(100, 4, 8), 256, 0, stream>>>(x, Xt);

    // conv1 + GN1 partial stats (no atomics)
    gemm_kernel<0><<<800, 256, 0, stream>>>(Xt, wb0, bufA, pscr0,
                                            nullptr, nullptr, nullptr, nullptr);
    reduce_stats_kernel<<<1, 256, 0, stream>>>(pscr0, stats);
    // GN1 + SiLU + Srow
    gn1_kernel<<<dim3(80, 8), 256, 0, stream>>>(bufA, bufB, Srow, stats, g1, b1);
    // Scol
    scol_kernel<<<dim3(10, 4, 8), 256, 0, stream>>>(bufB, Scol);
    // gate conv + fused-scan gating
    gemm_kernel<1><<<800, 256, 0, stream>>>(bufB, wb1, bufA, nullptr,
                                            bufB, Srow, Scol, b_gate);
    // depthwise 3x3
    dw_kernel<<<dim3(80, 2, 8), 256, 0, stream>>>(bufA, bufB, w_dw);
    // conv3 + GN2 partial stats (no atomics)
    gemm_kernel<2><<<800, 256, 0, stream>>>(bufB, wb2, bufA, pscr1,
                                            nullptr, nullptr, nullptr, nullptr);
    reduce_stats_kernel<<<1, 256, 0, stream>>>(pscr1, stats + 256);
    // GN2 + SiLU -> fp32 out (transposed)
    gn2T_kernel<<<dim3(100, 4, 8), 256, 0, stream>>>(bufA, out, stats, g2, b2);
}

// Round 5
// 305.617 us; speedup vs baseline: 1.3583x; 1.0456x over previous
//
#include <hip/hip_runtime.h>
#include <stdint.h>

#define CC 256
#define HH 80
#define WW 80
#define PP 6400          // 80*80
#define GG 16
#define GNCNT (16*6400)  // per (n,group): 16 channels * 6400 pixels
#define SAPAD 272        // sA row stride in u16 (padded 256->272)

using frag_ab = __attribute__((ext_vector_type(8))) short;   // 8 bf16 (4 VGPRs)
using frag_cd = __attribute__((ext_vector_type(4))) float;   // 4 fp32
typedef unsigned short u16;

__device__ __forceinline__ float b2f(u16 u) {
    union { float f; uint32_t i; } v; v.i = ((uint32_t)u) << 16; return v.f;
}
__device__ __forceinline__ u16 f2b(float f) {
    uint32_t x = __float_as_uint(f);
    return (u16)((x + 0x7fffu + ((x >> 16) & 1u)) >> 16);  // RNE
}
__device__ __forceinline__ float sigf(float x) { return 1.f / (1.f + __expf(-x)); }

// plain fp32 -> bf16 (weights)
__global__ __launch_bounds__(256) void cvt_kernel(const float* __restrict__ src,
                                                  u16* __restrict__ dst, int n4) {
    int i = blockIdx.x * 256 + threadIdx.x;
    if (i < n4) {
        float4 v = ((const float4*)src)[i];
        ushort4 o;
        o.x = f2b(v.x); o.y = f2b(v.y); o.z = f2b(v.z); o.w = f2b(v.w);
        ((ushort4*)dst)[i] = o;
    }
}

// ---------------------------------------------------------------------------
// GEMM: Out[m][o] = sum_c A[m][c] * W[o][c]; m = n*6400+p.
// Round-5: (a) MODE0 stages directly from fp32 x (cvtT's transpose-convert
// folded into the stage phase; cvtT kernel deleted, -52 MB net);
// (b) MODE1 reads the gate's h-tile from sA (it IS the staged A tile),
// prefetched to regs before the epilogue slab clobbers sA (-26 MB);
// (c) stats partials written contention-free to pscr (round-4 win kept);
// (d) __launch_bounds__(256,3): 3 blocks/CU, 800 blocks ~ 1 residency round.
// ---------------------------------------------------------------------------
template<int MODE>
__global__ __launch_bounds__(256, 3) void gemm_kernel(
    const u16* __restrict__ A,       // MODE1/2: [51200][256] bf16 (MODE0: unused)
    const u16* __restrict__ Wb,      // [256][256] bf16
    u16* __restrict__ Out,           // [51200][256] bf16
    float* __restrict__ pstats,      // MODE0/2: [800][32] per-block partials
    const float* __restrict__ Srow,  // MODE1: [8*80][256]
    const float* __restrict__ Scol,  // MODE1: [8*80][256]
    const float* __restrict__ bgate, // MODE1: [256]
    const float* __restrict__ Xf)    // MODE0: x fp32 [n][c][p]
{
    __shared__ __align__(16) u16 sA[64 * SAPAD];   // 34,816 B

    const int t    = threadIdx.x;
    const int lane = t & 63;
    const int wave = t >> 6;
    const int m    = lane & 15;
    const int q    = lane >> 4;
    const int mt   = blockIdx.x;
    const int m0   = mt * 64;
    const int n    = mt / 100;   // 100 blocks of 64 rows per n
    const int o0w  = wave * 64;  // wave's o-slice

    if (MODE == 0) {
        // ---- stage from x fp32 [c][p]: transpose-convert into sA[p][c] ----
        const int cl = t >> 2, pq = t & 3;
        const int p0 = m0 - n * PP;
        #pragma unroll
        for (int cb = 0; cb < 4; cb++) {
            const int c = cb * 64 + cl;
            const float* row = Xf + ((size_t)(n * CC + c)) * PP + p0 + pq * 16;
            #pragma unroll
            for (int u = 0; u < 4; u++) {
                float4 v = ((const float4*)(row + u * 4))[0];
                const int pp = pq * 16 + u * 4;
                sA[(pp + 0) * SAPAD + c] = f2b(v.x);
                sA[(pp + 1) * SAPAD + c] = f2b(v.y);
                sA[(pp + 2) * SAPAD + c] = f2b(v.z);
                sA[(pp + 3) * SAPAD + c] = f2b(v.w);
            }
        }
    } else {
        // ---- stage A chunk: 64 rows x 256 c, lane-contiguous bf16 loads ----
        const int row = t >> 2, qt = t & 3;
        const u16* g = A + (size_t)(m0 + row) * CC + qt * 64;
        u16* d = sA + row * SAPAD + qt * 64;
        #pragma unroll
        for (int i = 0; i < 8; i++)
            *(frag_ab*)(d + i * 8) = *(const frag_ab*)(g + i * 8);
    }
    __syncthreads();

    frag_cd acc[4][4];   // [msub][j]
    #pragma unroll
    for (int ms = 0; ms < 4; ms++)
        #pragma unroll
        for (int j = 0; j < 4; j++)
            #pragma unroll
            for (int k = 0; k < 4; k++) acc[ms][j][k] = 0.f;

    const u16* wl = Wb + (size_t)(o0w + m) * CC + q * 8;

    #pragma unroll
    for (int jh = 0; jh < 2; jh++) {
        // ---- W fragments for this 32-o half -> 64 VGPRs, one parallel batch ----
        frag_ab wf[2][8];
        #pragma unroll
        for (int jj = 0; jj < 2; jj++)
            #pragma unroll
            for (int kc = 0; kc < 8; kc++)
                wf[jj][kc] = *(const frag_ab*)(wl + (size_t)((jh * 2 + jj) * 16) * CC + kc * 32);
        // pin: forbid rematerialization/sinking of the W loads
        #pragma unroll
        for (int jj = 0; jj < 2; jj++)
            #pragma unroll
            for (int kc = 0; kc < 8; kc++)
                asm volatile("" : "+v"(wf[jj][kc]));

        #pragma unroll
        for (int ms = 0; ms < 4; ms++) {
            #pragma unroll
            for (int kc = 0; kc < 8; kc++) {
                frag_ab af = *(const frag_ab*)(sA + (ms * 16 + m) * SAPAD + kc * 32 + q * 8);
                #pragma unroll
                for (int jj = 0; jj < 2; jj++)
                    acc[ms][jh * 2 + jj] = __builtin_amdgcn_mfma_f32_16x16x32_bf16(
                        af, wf[jj][kc], acc[ms][jh * 2 + jj], 0, 0, 0);
            }
        }
    }

    // MODE1: prefetch the gate's h values FROM sA (== the staged A tile) into
    // registers BEFORE the barrier releases the epilogue slab writes.
    ushort4 hv[4][4];
    if (MODE == 1) {
        const int rr0 = lane >> 4;
        const int cH  = o0w + (lane & 15) * 4;
        #pragma unroll
        for (int ms = 0; ms < 4; ms++)
            #pragma unroll
            for (int u = 0; u < 4; u++)
                hv[ms][u] = *(const ushort4*)(sA + (size_t)(ms * 16 + u * 4 + rr0) * SAPAD + cH);
    }
    __syncthreads();   // all waves done reading sA; reuse as epilogue scratch

    if (MODE == 0 || MODE == 2) {
        #pragma unroll
        for (int j = 0; j < 4; j++) {
            float s = 0.f, sq = 0.f;
            #pragma unroll
            for (int ms = 0; ms < 4; ms++)
                #pragma unroll
                for (int r = 0; r < 4; r++) {
                    float v = acc[ms][j][r];
                    s += v; sq += v * v;
                }
            #pragma unroll
            for (int off = 32; off > 0; off >>= 1) {
                s  += __shfl_down(s, off);
                sq += __shfl_down(sq, off);
            }
            if (lane == 0) {
                // contention-free per-block partials (group = wave*4 + j)
                float* p = pstats + (size_t)mt * 32;
                p[wave * 4 + j]      = s;
                p[16 + wave * 4 + j] = sq;
            }
        }
        // repack per 16-row subtile through private slab -> 16B stores
        u16* myT = sA + wave * 1152;   // 16x72 u16
        #pragma unroll
        for (int ms = 0; ms < 4; ms++) {
            #pragma unroll
            for (int j = 0; j < 4; j++)
                #pragma unroll
                for (int r = 0; r < 4; r++)
                    myT[(q * 4 + r) * 72 + j * 16 + m] = f2b(acc[ms][j][r]);
            #pragma unroll
            for (int u = 0; u < 2; u++) {
                const int rr = u * 8 + (lane >> 3);
                frag_ab v = *(const frag_ab*)(myT + rr * 72 + (lane & 7) * 8);
                *(frag_ab*)(Out + (size_t)(m0 + ms * 16 + rr) * CC + o0w + (lane & 7) * 8) = v;
            }
        }
    } else {
        float* myG = (float*)sA + wave * 1152;   // 16x72 fp32
        float bg[4];
        #pragma unroll
        for (int j = 0; j < 4; j++) bg[j] = bgate[o0w + j * 16 + m];
        #pragma unroll
        for (int ms = 0; ms < 4; ms++) {
            #pragma unroll
            for (int j = 0; j < 4; j++)
                #pragma unroll
                for (int r = 0; r < 4; r++)
                    myG[(q * 4 + r) * 72 + j * 16 + m] = sigf(acc[ms][j][r] + bg[j]);
            #pragma unroll
            for (int u = 0; u < 4; u++) {
                const int rr  = u * 4 + (lane >> 4);
                const int col = (lane & 15) * 4;
                float4 g4 = *(const float4*)(myG + rr * 72 + col);
                const int row = m0 + ms * 16 + rr;
                const int pl  = row - n * PP;
                const int pr  = pl / WW;
                const int pc  = pl - pr * WW;
                const int o   = o0w + col;
                ushort4 hq = hv[ms][u];
                float4  sr = *(const float4*)(Srow + (size_t)(n * HH + pr) * CC + o);
                float4  sc = *(const float4*)(Scol + (size_t)(n * HH + pc) * CC + o);
                ushort4 ov;
                ov.x = f2b(0.25f * (sr.x + sc.x + 2.f * b2f(hq.x)) * g4.x);
                ov.y = f2b(0.25f * (sr.y + sc.y + 2.f * b2f(hq.y)) * g4.y);
                ov.z = f2b(0.25f * (sr.z + sc.z + 2.f * b2f(hq.z)) * g4.z);
                ov.w = f2b(0.25f * (sr.w + sc.w + 2.f * b2f(hq.w)) * g4.w);
                *(ushort4*)(Out + (size_t)row * CC + o) = ov;
            }
        }
    }
}

// GN1 + SiLU + Srow.  Block per (i-row, n): 80 j x 256 c.
// Round-5: stats reduce INLINED (t<32 sum the 100 per-block partials).
__global__ __launch_bounds__(256) void gn1_kernel(
    const u16* __restrict__ c1, u16* __restrict__ hb,
    float* __restrict__ Srow,
    const float* __restrict__ pscr,   // [800][32]
    const float* __restrict__ g1, const float* __restrict__ b1)
{
    __shared__ float sred[8 * 256];
    __shared__ float sstat[32];
    const int i = blockIdx.x, n = blockIdx.y;
    const int t = threadIdx.x;
    if (t < 32) {
        const int kind = t >> 4, g = t & 15;
        const float* p = pscr + (size_t)(n * 100) * 32 + kind * 16 + g;
        float s = 0.f;
        #pragma unroll 4
        for (int ii = 0; ii < 100; ii++) s += p[ii * 32];
        sstat[t] = s;
    }
    __syncthreads();

    const int jg = t >> 5, cc = t & 31;
    const int c8 = cc * 8;
    const int g  = cc >> 1;   // group of this 8c chunk
    const float su   = sstat[g];
    const float sq   = sstat[16 + g];
    const float mean = su * (1.f / GNCNT);
    const float var  = sq * (1.f / GNCNT) - mean * mean;
    const float inv  = rsqrtf(var + 1e-5f);
    float a[8], b[8];
    #pragma unroll
    for (int k = 0; k < 8; k++) {
        a[k] = inv * g1[c8 + k];
        b[k] = b1[c8 + k] - mean * a[k];
    }
    float srow8[8];
    #pragma unroll
    for (int k = 0; k < 8; k++) srow8[k] = 0.f;

    const size_t base = (size_t)(n * PP + i * WW) * CC;
    for (int s = 0; s < 10; s++) {
        const int j = jg + s * 8;
        const u16* src = c1 + base + (size_t)j * CC + c8;
        u16*       dst = hb + base + (size_t)j * CC + c8;
        frag_ab v = *(const frag_ab*)src;
        frag_ab o;
        #pragma unroll
        for (int k = 0; k < 8; k++) {
            float xn = b2f((u16)v[k]) * a[k] + b[k];
            float hs = xn * sigf(xn);
            o[k] = (short)f2b(hs);
            srow8[k] += hs;
        }
        *(frag_ab*)dst = o;
    }
    #pragma unroll
    for (int k = 0; k < 8; k++) sred[jg * 256 + c8 + k] = srow8[k];
    __syncthreads();
    {
        const int c = t;
        float s = 0.f;
        #pragma unroll
        for (int k = 0; k < 8; k++) s += sred[k * 256 + c];
        Srow[(size_t)(n * HH + i) * CC + c] = s;
    }
}

// Scol[n][j][c] = sum_i hs[n][i*80+j][c].  Block (jg, iq, n); atomics (Scol pre-zeroed).
__global__ __launch_bounds__(256) void scol_kernel(
    const u16* __restrict__ hb, float* __restrict__ Scol)
{
    const int jg = blockIdx.x, iq = blockIdx.y, n = blockIdx.z;
    const int t = threadIdx.x;
    const int js = t >> 5, cc = t & 31;
    const int j = jg * 8 + js, c8 = cc * 8;
    float acc8[8];
    #pragma unroll
    for (int k = 0; k < 8; k++) acc8[k] = 0.f;
    for (int s = 0; s < 20; s++) {
        const int i = iq * 20 + s;
        frag_ab v = *(const frag_ab*)(hb + (size_t)(n * PP + i * WW + j) * CC + c8);
        #pragma unroll
        for (int k = 0; k < 8; k++) acc8[k] += b2f((u16)v[k]);
    }
    float* dst = Scol + (size_t)(n * HH + j) * CC + c8;
    #pragma unroll
    for (int k = 0; k < 8; k++) atomicAdd(&dst[k], acc8[k]);
}

// depthwise 3x3 zero-pad in [p][c] layout.  Block (i, chalf, n).
__global__ __launch_bounds__(256) void dw_kernel(
    const u16* __restrict__ gin, u16* __restrict__ dout,
    const float* __restrict__ wdw)
{
    __shared__ float sw[1152];   // 128 c * 9
    const int i = blockIdx.x, chalf = blockIdx.y, n = blockIdx.z;
    const int t = threadIdx.x;
    for (int u = t; u < 1152; u += 256) sw[u] = wdw[chalf * 1152 + u];
    __syncthreads();

    const int jg = t >> 5, cc = t & 31;
    const int gc = chalf * 128 + cc * 4;   // global c of 4-chunk
    float wl[4][9];
    #pragma unroll
    for (int cl = 0; cl < 4; cl++)
        #pragma unroll
        for (int k = 0; k < 9; k++) wl[cl][k] = sw[(cc * 4 + cl) * 9 + k];

    const size_t nbase = (size_t)n * PP * CC;
    for (int s = 0; s < 10; s++) {
        const int j = jg + s * 8;
        float acc4[4] = {0.f, 0.f, 0.f, 0.f};
        #pragma unroll
        for (int di = -1; di <= 1; di++) {
            const int ii = i + di;
            if (ii < 0 || ii >= HH) continue;
            #pragma unroll
            for (int dj = -1; dj <= 1; dj++) {
                const int jj = j + dj;
                if (jj < 0 || jj >= WW) continue;
                ushort4 v = *(const ushort4*)(gin + nbase + (size_t)(ii * WW + jj) * CC + gc);
                const int k = (di + 1) * 3 + (dj + 1);
                acc4[0] += wl[0][k] * b2f(v.x);
                acc4[1] += wl[1][k] * b2f(v.y);
                acc4[2] += wl[2][k] * b2f(v.z);
                acc4[3] += wl[3][k] * b2f(v.w);
            }
        }
        ushort4 o;
        o.x = f2b(acc4[0]); o.y = f2b(acc4[1]); o.z = f2b(acc4[2]); o.w = f2b(acc4[3]);
        *(ushort4*)(dout + nbase + (size_t)(i * WW + j) * CC + gc) = o;
    }
}

// GN2 + SiLU + transpose-out: Y [n][p][c] bf16 -> out [n][c][p] fp32.  64p x 64c tile.
// Round-5: stats reduce INLINED from pscr1.
__global__ __launch_bounds__(256) void gn2T_kernel(
    const u16* __restrict__ Y, float* __restrict__ out,
    const float* __restrict__ pscr,   // [800][32]
    const float* __restrict__ g2, const float* __restrict__ b2v)
{
    __shared__ u16 sT[64 * 72];
    __shared__ float sstat[32];
    const int p0 = blockIdx.x * 64, c0 = blockIdx.y * 64, n = blockIdx.z;
    const int t = threadIdx.x;
    if (t < 32) {
        const int kind = t >> 4, g = t & 15;
        const float* p = pscr + (size_t)(n * 100) * 32 + kind * 16 + g;
        float s = 0.f;
        #pragma unroll 4
        for (int ii = 0; ii < 100; ii++) s += p[ii * 32];
        sstat[t] = s;
    }
    {   // phase 1: read Y rows (coalesced along c)
        const int pl = t >> 2, cq = t & 3;
        const u16* row = Y + (size_t)(n * PP + p0 + pl) * CC + c0 + cq * 16;
        *(frag_ab*)(sT + pl * 72 + cq * 16)     = *(const frag_ab*)(row);
        *(frag_ab*)(sT + pl * 72 + cq * 16 + 8) = *(const frag_ab*)(row + 8);
    }
    __syncthreads();
    {   // phase 2: per-c affine + silu, write out rows (coalesced along p)
        const int cl = t >> 2, pq = t & 3;
        const int c = c0 + cl, g = c >> 4;
        const float su   = sstat[g];
        const float sq   = sstat[16 + g];
        const float mean = su * (1.f / GNCNT);
        const float var  = sq * (1.f / GNCNT) - mean * mean;
        const float inv  = rsqrtf(var + 1e-5f);
        const float a    = inv * g2[c];
        const float b    = b2v[c] - mean * a;
        float* orow = out + (size_t)(n * CC + c) * PP + p0 + pq * 16;
        #pragma unroll
        for (int u4 = 0; u4 < 4; u4++) {
            float4 o;
            float* op = (float*)&o;
            #pragma unroll
            for (int e = 0; e < 4; e++) {
                const int pp = pq * 16 + u4 * 4 + e;
                float xn = b2f(sT[pp * 72 + cl]) * a + b;
                op[e] = xn * sigf(xn);
            }
            ((float4*)(orow + u4 * 4))[0] = o;
        }
    }
}

extern "C" void kernel_launch(void* const* d_in, const int* in_sizes, int n_in,
                              void* d_out, int out_size, void* d_ws, size_t ws_size,
                              hipStream_t stream)
{
    const float* x      = (const float*)d_in[0];
    const float* w_pre  = (const float*)d_in[1];
    const float* g1     = (const float*)d_in[2];
    const float* b1     = (const float*)d_in[3];
    const float* w_gate = (const float*)d_in[4];
    const float* b_gate = (const float*)d_in[5];
    const float* w_dw   = (const float*)d_in[6];
    const float* w_pw   = (const float*)d_in[7];
    const float* g2     = (const float*)d_in[8];
    const float* b2     = (const float*)d_in[9];
    float* out = (float*)d_out;

    char* ws = (char*)d_ws;
    u16*   wb0   = (u16*)(ws);                      // 131,072 B
    u16*   wb1   = (u16*)(ws + 131072);             // 131,072 B
    u16*   wb2   = (u16*)(ws + 262144);             // 131,072 B
    // (ws + 393216 .. 26,607,616: former Xt slot, now unused)
    u16*   bufA  = (u16*)(ws + 26607616);           // 26,214,400 B
    u16*   bufB  = (u16*)(ws + 52822016);           // 26,214,400 B
    float* Srow  = (float*)(ws + 79036416);         // 655,360 B
    float* Scol  = (float*)(ws + 79691776);         // 655,360 B
    float* pscr0 = (float*)(ws + 80347136);         // 102,400 B (dedicated!)
    float* pscr1 = (float*)(ws + 80449536);         // 102,400 B (dedicated!)

    hipMemsetAsync(Scol, 0, 655360, stream);

    cvt_kernel<<<64, 256, 0, stream>>>(w_pre,  wb0, 16384);
    cvt_kernel<<<64, 256, 0, stream>>>(w_gate, wb1, 16384);
    cvt_kernel<<<64, 256, 0, stream>>>(w_pw,   wb2, 16384);

    // conv1 (stages directly from fp32 x, transpose fused) + GN1 partial stats
    gemm_kernel<0><<<800, 256, 0, stream>>>(nullptr, wb0, bufA, pscr0,
                                            nullptr, nullptr, nullptr, x);
    // GN1 + SiLU + Srow (stats reduce inlined)
    gn1_kernel<<<dim3(80, 8), 256, 0, stream>>>(bufA, bufB, Srow, pscr0, g1, b1);
    // Scol
    scol_kernel<<<dim3(10, 4, 8), 256, 0, stream>>>(bufB, Scol);
    // gate conv + fused-scan gating (h read from LDS tile)
    gemm_kernel<1><<<800, 256, 0, stream>>>(bufB, wb1, bufA, nullptr,
                                            Srow, Scol, b_gate, nullptr);
    // depthwise 3x3
    dw_kernel<<<dim3(80, 2, 8), 256, 0, stream>>>(bufA, bufB, w_dw);
    // conv3 + GN2 partial stats
    gemm_kernel<2><<<800, 256, 0, stream>>>(bufB, wb2, bufA, pscr1,
                                            nullptr, nullptr, nullptr, nullptr);
    // GN2 + SiLU -> fp32 out (transposed; stats reduce inlined)
    gn2T_kernel<<<dim3(100, 4, 8), 256, 0, stream>>>(bufA, out, pscr1, g2, b2);
}